// Round 10
// baseline (18022.784 us; speedup 1.0000x reference)
//
#include <hip/hip_runtime.h>
#include <stdint.h>

// Problem dims
#define TT 2048
#define BB 32
#define II 256
#define HH 512
#define OO 1024
#define NWGL 64    // WGs per layer (each owns 8 hidden units = 32 gate columns)
#define NWG 128
#define RING 32    // ring slots per layer (32 KB each)
#define NREP 8     // seq-tag replication factor (contention spread)
#define SLOTB (BB * HH * 2)
#define SEQN (NREP * RING * 64)

typedef __attribute__((ext_vector_type(8))) short short8;
typedef __attribute__((ext_vector_type(4))) float floatx4;

__device__ __forceinline__ unsigned short f2bf(float f) {
  union { float f; unsigned u; } v; v.f = f;
  unsigned r = v.u + 0x7FFFu + ((v.u >> 16) & 1u);  // RNE
  return (unsigned short)(r >> 16);
}
__device__ __forceinline__ float bf2f(unsigned short b) {
  union { float f; unsigned u; } v; v.u = ((unsigned)b) << 16; return v.f;
}
__device__ __forceinline__ float sigmf(float x) { return 1.0f / (1.0f + __expf(-x)); }
__device__ __forceinline__ float tanhfast(float x) {
  float xc = fminf(fmaxf(x, -15.f), 15.f);
  float e = __expf(2.f * xc);
  return (e - 1.f) / (e + 1.f);
}

// Coherent (MALL) 16B load via 64-bit VGPR address: d <- [va + IMM].
#define LD1(d, va, IMM)                                                     \
  asm volatile("global_load_dwordx4 %0, %1, off offset:" IMM " sc0 sc1"     \
               : "=v"(d) : "v"(va) : "memory")
// Cached 16B load (normal L1/L2 path) — read-only x.
#define LD1C(d, va, IMM)                                                    \
  asm volatile("global_load_dwordx4 %0, %1, off offset:" IMM                \
               : "=v"(d) : "v"(va) : "memory")

#define ISSUE8(dst, va) do {                                                \
    LD1(dst[0], va, "0");   LD1(dst[1], va, "64");                          \
    LD1(dst[2], va, "128"); LD1(dst[3], va, "192");                         \
    LD1(dst[4], va, "256"); LD1(dst[5], va, "320");                         \
    LD1(dst[6], va, "384"); LD1(dst[7], va, "448"); } while (0)
#define ISSUE8C(dst, va) do {                                               \
    LD1C(dst[0], va, "0");   LD1C(dst[1], va, "64");                        \
    LD1C(dst[2], va, "128"); LD1C(dst[3], va, "192");                       \
    LD1C(dst[4], va, "256"); LD1C(dst[5], va, "320");                       \
    LD1C(dst[6], va, "384"); LD1C(dst[7], va, "448"); } while (0)

// Wait until <=N vector-mem ops outstanding; fence the scheduler (rule #18).
#define WAITV(N) do {                                                       \
    asm volatile("s_waitcnt vmcnt(" #N ")" ::: "memory");                   \
    __builtin_amdgcn_sched_barrier(0); } while (0)

#define MF8(tt_, src, wbase) do {                                           \
    _Pragma("unroll")                                                       \
    for (int j = 0; j < 8; j++) {                                           \
      acc[0][tt_] = __builtin_amdgcn_mfma_f32_16x16x32_bf16(src[j], wf[0][(wbase) + j], acc[0][tt_], 0, 0, 0); \
      acc[1][tt_] = __builtin_amdgcn_mfma_f32_16x16x32_bf16(src[j], wf[1][(wbase) + j], acc[1][tt_], 0, 0, 0); \
    } } while (0)

// Coherent dword load (seq words).
#define PROGREAD(dst, addr64)                                               \
  asm volatile("global_load_dword %0, %1, off sc0 sc1"                      \
               : "=v"(dst) : "v"(addr64) : "memory")

// Publish seq word into all NREP replicas (lane 0, pipelined stores).
#define SEQSTORE(arr, slot, val) do {                                       \
    if (lane == 0) {                                                        \
      _Pragma("unroll")                                                     \
      for (int _r = 0; _r < NREP; _r++) {                                   \
        unsigned long long _a = (unsigned long long)(arr) +                 \
            (unsigned long long)(_r * RING * 64 + (slot) * 64 + g) * 4;     \
        int _v = (val);                                                     \
        asm volatile("global_store_dword %0, %1, off sc0 sc1"               \
                     :: "v"(_a), "v"(_v) : "memory");                       \
      }                                                                     \
    } } while (0)

// Validate slot tag on THIS wave's replica (repoff) — 8 pollers/line not 64.
#define VALIDATE(arr, slot, tag) do {                                       \
    const unsigned long long _sa = (unsigned long long)(arr) +              \
        (unsigned long long)(repoff + (slot) * 64 + lane) * 4;              \
    int _sv; PROGREAD(_sv, _sa); WAITV(0);                                  \
    while (!__all(_sv == (tag))) {                                          \
      __builtin_amdgcn_s_sleep(2); PROGREAD(_sv, _sa); WAITV(0);            \
    } } while (0)
#define GUARDGE(arr, slot, tag) do {                                        \
    const unsigned long long _sa = (unsigned long long)(arr) +              \
        (unsigned long long)(repoff + (slot) * 64 + lane) * 4;              \
    int _sv; PROGREAD(_sv, _sa); WAITV(0);                                  \
    while (!__all(_sv >= (tag))) {                                          \
      __builtin_amdgcn_s_sleep(4); PROGREAD(_sv, _sa); WAITV(0);            \
    } } while (0)

// Gate nonlinearities + c/h update + LDS pack + coalesced coherent store.
#define TAIL(hwaddr) do {                                                   \
  _Pragma("unroll")                                                         \
  for (int tau = 0; tau < 2; tau++) {                                       \
    _Pragma("unroll")                                                       \
    for (int tt = 0; tt < 2; tt++) {                                        \
      _Pragma("unroll")                                                     \
      for (int r = 0; r < 4; r++) {                                         \
        float val = acc[tau][tt][r];                                        \
        float nl = (gate == 2) ? tanhfast(val) : sigmf(val);                \
        int base2 = (lane & 48) | u;                                        \
        float iv = __shfl(nl, base2);                                       \
        float fv = __shfl(nl, base2 | 4);                                   \
        float gv = __shfl(nl, base2 | 8);                                   \
        float ov = __shfl(nl, base2 | 12);                                  \
        if (gate == 0) {                                                    \
          float cn = fv * cst[tau][tt][r] + iv * gv;                        \
          cst[tau][tt][r] = cn;                                             \
          float hn = ov * tanhfast(cn);                                     \
          int b = tt * 16 + krow * 4 + r;                                   \
          sh[b][tau * 4 + u] = f2bf(hn);                                    \
        }                                                                   \
      }                                                                     \
    }                                                                       \
  }                                                                         \
  asm volatile("s_waitcnt lgkmcnt(0)" ::: "memory");                        \
  __builtin_amdgcn_sched_barrier(0);                                        \
  if (lane < 32) {                                                          \
    short8 v = *reinterpret_cast<const short8*>(&sh[lane][0]);              \
    unsigned long long sa = (hwaddr) + stoff;                               \
    asm volatile("global_store_dwordx4 %0, %1, off sc0 sc1"                 \
                 :: "v"(sa), "v"(v) : "memory");                            \
  } } while (0)

// Rotated-order load+MFMA bodies (K-accumulation commutes; rotation spreads
// simultaneous line demand across 4 chunk groups). wf indices are literals
// in every instantiation (rule #20: no runtime register indexing).
#define L0BODY(A0,W0,T0, A1,W1,T1, A2,W2,T2, A3,W3,T3) do {                 \
    ISSUE8(wa, A0); ISSUE8(wb, A1); ISSUE8(wc, A2); ISSUE8(wd, A3);         \
    WAITV(24); MF8(T0, wa, W0); ISSUE8C(wa, xa);                            \
    WAITV(24); MF8(T1, wb, W1); ISSUE8C(wb, xa + 8192);                     \
    WAITV(24); MF8(T2, wc, W2);                                             \
    WAITV(16); MF8(T3, wd, W3);                                             \
    WAITV(8);  MF8(0, wa, 0);                                               \
    WAITV(0);  MF8(1, wb, 0); } while (0)

#define L1BODY(A0,W0,T0, A1,W1,T1, A2,W2,T2, A3,W3,T3,                      \
               A4,W4,T4, A5,W5,T5, A6,W6,T6, A7,W7,T7) do {                 \
    ISSUE8(wa, A0); ISSUE8(wb, A1); ISSUE8(wc, A2); ISSUE8(wd, A3);         \
    WAITV(24); MF8(T0, wa, W0); ISSUE8(wa, A4);                             \
    WAITV(24); MF8(T1, wb, W1); ISSUE8(wb, A5);                             \
    WAITV(24); MF8(T2, wc, W2); ISSUE8(wc, A6);                             \
    WAITV(24); MF8(T3, wd, W3); ISSUE8(wd, A7);                             \
    WAITV(24); MF8(T4, wa, W4);                                             \
    WAITV(16); MF8(T5, wb, W5);                                             \
    WAITV(8);  MF8(T6, wc, W6);                                             \
    WAITV(0);  MF8(T7, wd, W7); } while (0)

// ---------------- x fp32 -> bf16 convert ----------------
__global__ void k_convert_x(const float* __restrict__ x, ushort* __restrict__ xb, int n4) {
  int i = blockIdx.x * blockDim.x + threadIdx.x;
  int stride = gridDim.x * blockDim.x;
  const float4* xf = reinterpret_cast<const float4*>(x);
  ushort4* ob = reinterpret_cast<ushort4*>(xb);
  for (; i < n4; i += stride) {
    float4 f = xf[i];
    ushort4 o;
    o.x = f2bf(f.x); o.y = f2bf(f.y); o.z = f2bf(f.z); o.w = f2bf(f.w);
    ob[i] = o;
  }
}

// ---------------- init: ring slot 31 = initial h, seed all seq replicas ----
__global__ void k_init(const float* __restrict__ h0in,
                       ushort* __restrict__ h0ring, ushort* __restrict__ h1ring,
                       int* __restrict__ h0seq, int* __restrict__ h1seq) {
  int i = threadIdx.x;
  ushort* s0 = h0ring + (RING - 1) * BB * HH;
  ushort* s1 = h1ring + (RING - 1) * BB * HH;
  for (int k = i; k < BB * HH; k += blockDim.x) {
    s0[k] = f2bf(h0in[k]);
    s1[k] = f2bf(h0in[BB * HH + k]);
  }
  for (int k = i; k < SEQN; k += blockDim.x) {
    int slot = (k % (RING * 64)) / 64;
    int v = (slot == RING - 1) ? -1 : (int)0x80000000;  // slot31 tag -1
    h0seq[k] = v;
    h1seq[k] = v;
  }
}

// ---------------- persistent recurrence kernel (r6 semantics + anti-contention)
__global__ __launch_bounds__(64, 1) void k_lstm(
    const ushort* __restrict__ xb,
    const float* __restrict__ w_ih0, const float* __restrict__ w_hh0,
    const float* __restrict__ b_ih0, const float* __restrict__ b_hh0,
    const float* __restrict__ w_ih1, const float* __restrict__ w_hh1,
    const float* __restrict__ b_ih1, const float* __restrict__ b_hh1,
    const float* __restrict__ c0in,
    ushort* __restrict__ h0ring, ushort* __restrict__ h1ring,
    int* __restrict__ h0seq, int* __restrict__ h1seq)
{
  __shared__ ushort sh[BB][8];  // 512B store-coalescing tile
  const int wg = blockIdx.x;
  const int lane = threadIdx.x;
  const bool isL0 = wg < NWGL;
  const int g = isL0 ? wg : wg - NWGL;
  const int col = lane & 15;
  const int krow = lane >> 4;
  const int u = col & 3;
  const int gate = col >> 2;  // 0=i 1=f 2=g 3=o
  const int repoff = (g & (NREP - 1)) * RING * 64;
  const int rot = g & 3;

  // --- pack weight B-fragments into registers (bf16) ---
  short8 wf[2][32];
#define LOADW(dst, base, rowlen, kbase, tau) do {                             \
    const int _grow = gate * HH + g * 8 + (tau) * 4 + u;                      \
    const float* _p = (base) + (size_t)_grow * (rowlen) + (kbase) + krow * 8; \
    short8 _r;                                                                \
    _Pragma("unroll")                                                         \
    for (int _j = 0; _j < 8; _j++) _r[_j] = (short)f2bf(_p[_j]);              \
    (dst) = _r; } while (0)

  if (isL0) {
#pragma unroll
    for (int tau = 0; tau < 2; tau++) {
#pragma unroll
      for (int kk = 0; kk < 8; kk++)  LOADW(wf[tau][kk],      w_ih0, II, kk * 32, tau);
#pragma unroll
      for (int kk = 0; kk < 16; kk++) LOADW(wf[tau][8 + kk],  w_hh0, HH, kk * 32, tau);
    }
  } else {
#pragma unroll
    for (int tau = 0; tau < 2; tau++) {
#pragma unroll
      for (int kk = 0; kk < 16; kk++) LOADW(wf[tau][kk],      w_ih1, HH, kk * 32, tau);
#pragma unroll
      for (int kk = 0; kk < 16; kk++) LOADW(wf[tau][16 + kk], w_hh1, HH, kk * 32, tau);
    }
  }
  float bias[2];
#pragma unroll
  for (int tau = 0; tau < 2; tau++) {
    const int grow = gate * HH + g * 8 + tau * 4 + u;
    bias[tau] = isL0 ? (b_ih0[grow] + b_hh0[grow]) : (b_ih1[grow] + b_hh1[grow]);
  }

  // --- c state in fp32 registers (used in gate==0 lanes) ---
  float cst[2][2][4];
  {
    const float* cbase = c0in + (isL0 ? 0 : 1) * BB * HH;
#pragma unroll
    for (int tau = 0; tau < 2; tau++)
#pragma unroll
      for (int tt = 0; tt < 2; tt++)
#pragma unroll
        for (int r = 0; r < 4; r++) {
          int b = tt * 16 + krow * 4 + r;
          cst[tau][tt][r] = cbase[b * HH + g * 8 + tau * 4 + u];
        }
  }

  const unsigned long long h0rb = (unsigned long long)h0ring;
  const unsigned long long h1rb = (unsigned long long)h1ring;
  const int vo00 = col * 1024 + krow * 16;  // [32][512]bf16 tile; tt=1 = +16384
  const unsigned long long stoff = (unsigned long long)(lane * 1024 + g * 16);

  short8 wa[8], wb[8], wc[8], wd[8];
  floatx4 acc[2][2];
  const floatx4 bi0 = (floatx4){ bias[0], bias[0], bias[0], bias[0] };
  const floatx4 bi1 = (floatx4){ bias[1], bias[1], bias[1], bias[1] };

  if (isL0) {
    // =============== layer 0 loop ===============
    const unsigned long long xbase = (unsigned long long)xb + (col * 512 + krow * 16);
    for (int t = 0; t < TT; ++t) {
      VALIDATE(h0seq, (t + 31) & 31, t - 1);
      if (((t & 7) == 0) && t >= 32) GUARDGE(h1seq, (t - 24) & 31, t - 24);
      acc[0][0] = bi0; acc[0][1] = bi0; acc[1][0] = bi1; acc[1][1] = bi1;
      const unsigned long long ha = h0rb + (unsigned long long)((t + 31) & 31) * SLOTB + vo00;
      const unsigned long long xa = xbase + (unsigned long long)t * (BB * II * 2);
      switch (rot) {
        case 0:  L0BODY(ha,8,0,        ha+512,16,0,   ha+16384,8,1,  ha+16896,16,1); break;
        case 1:  L0BODY(ha+512,16,0,   ha+16384,8,1,  ha+16896,16,1, ha,8,0);        break;
        case 2:  L0BODY(ha+16384,8,1,  ha+16896,16,1, ha,8,0,        ha+512,16,0);   break;
        default: L0BODY(ha+16896,16,1, ha,8,0,        ha+512,16,0,   ha+16384,8,1);  break;
      }
      TAIL(h0rb + (unsigned long long)(t & 31) * SLOTB);
      WAITV(0);                        // drain data stores
      SEQSTORE(h0seq, (t & 31), t);    // publish (8 replicas)
    }
  } else {
    // =============== layer 1 loop ===============
    for (int t = 0; t < TT; ++t) {
      {
        const unsigned long long sa0 = (unsigned long long)h0seq +
            (unsigned long long)(repoff + (t & 31) * 64 + lane) * 4;
        const unsigned long long sa1 = (unsigned long long)h1seq +
            (unsigned long long)(repoff + ((t + 31) & 31) * 64 + lane) * 4;
        int s0, s1; PROGREAD(s0, sa0); PROGREAD(s1, sa1); WAITV(0);
        while (!(__all(s0 == t) & __all(s1 == t - 1))) {
          __builtin_amdgcn_s_sleep(2);
          PROGREAD(s0, sa0); PROGREAD(s1, sa1); WAITV(0);
        }
      }
      acc[0][0] = bi0; acc[0][1] = bi0; acc[1][0] = bi1; acc[1][1] = bi1;
      const unsigned long long a0 = h0rb + (unsigned long long)(t & 31) * SLOTB + vo00;
      const unsigned long long a1 = h1rb + (unsigned long long)((t + 31) & 31) * SLOTB + vo00;
      switch (rot) {
        case 0:
          L1BODY(a0,0,0,       a0+512,8,0,    a0+16384,0,1,  a0+16896,8,1,
                 a1,16,0,      a1+512,24,0,   a1+16384,16,1, a1+16896,24,1);
          break;
        case 1:
          L1BODY(a0+16384,0,1, a0+16896,8,1,  a1,16,0,       a1+512,24,0,
                 a1+16384,16,1,a1+16896,24,1, a0,0,0,        a0+512,8,0);
          break;
        case 2:
          L1BODY(a1,16,0,      a1+512,24,0,   a1+16384,16,1, a1+16896,24,1,
                 a0,0,0,       a0+512,8,0,    a0+16384,0,1,  a0+16896,8,1);
          break;
        default:
          L1BODY(a1+16384,16,1,a1+16896,24,1, a0,0,0,        a0+512,8,0,
                 a0+16384,0,1, a0+16896,8,1,  a1,16,0,       a1+512,24,0);
          break;
      }
      TAIL(h1rb + (unsigned long long)(t & 31) * SLOTB);
      WAITV(0);                        // drain data stores
      SEQSTORE(h1seq, (t & 31), t);    // publish (8 replicas)
    }
  }
}

// ---------------- FC + log_softmax ----------------
__global__ __launch_bounds__(256) void k_fc(const ushort* __restrict__ h1,
                                            const float* __restrict__ fcw,
                                            const float* __restrict__ fcb,
                                            float* __restrict__ out) {
  __shared__ float hsh[HH];
  __shared__ float red[256];
  const int b = blockIdx.x, tid = threadIdx.x;
  for (int k = tid; k < HH; k += 256) hsh[k] = bf2f(h1[b * HH + k]);
  __syncthreads();
  float lg[4];
#pragma unroll
  for (int q = 0; q < 4; q++) {
    int o = q * 256 + tid;
    float acc = fcb[o];
    const float* wr = fcw + (size_t)o * HH;
#pragma unroll 4
    for (int k = 0; k < HH; k += 4) {
      float4 w4 = *reinterpret_cast<const float4*>(wr + k);
      acc += hsh[k] * w4.x + hsh[k + 1] * w4.y + hsh[k + 2] * w4.z + hsh[k + 3] * w4.w;
    }
    lg[q] = acc;
  }
  float m = fmaxf(fmaxf(lg[0], lg[1]), fmaxf(lg[2], lg[3]));
  red[tid] = m; __syncthreads();
  for (int s = 128; s > 0; s >>= 1) { if (tid < s) red[tid] = fmaxf(red[tid], red[tid + s]); __syncthreads(); }
  m = red[0]; __syncthreads();
  float se = 0.f;
#pragma unroll
  for (int q = 0; q < 4; q++) se += __expf(lg[q] - m);
  red[tid] = se; __syncthreads();
  for (int s = 128; s > 0; s >>= 1) { if (tid < s) red[tid] += red[tid + s]; __syncthreads(); }
  float lse = m + logf(red[0]);
#pragma unroll
  for (int q = 0; q < 4; q++) out[b * OO + q * 256 + tid] = lg[q] - lse;
}

extern "C" void kernel_launch(void* const* d_in, const int* in_sizes, int n_in,
                              void* d_out, int out_size, void* d_ws, size_t ws_size,
                              hipStream_t stream) {
  const float* x     = (const float*)d_in[0];
  const float* h0    = (const float*)d_in[1];
  const float* c0    = (const float*)d_in[2];
  const float* w_ih0 = (const float*)d_in[3];
  const float* w_hh0 = (const float*)d_in[4];
  const float* b_ih0 = (const float*)d_in[5];
  const float* b_hh0 = (const float*)d_in[6];
  const float* w_ih1 = (const float*)d_in[7];
  const float* w_hh1 = (const float*)d_in[8];
  const float* b_ih1 = (const float*)d_in[9];
  const float* b_hh1 = (const float*)d_in[10];
  const float* fcw   = (const float*)d_in[11];
  const float* fcb   = (const float*)d_in[12];
  float* out = (float*)d_out;

  char* ws = (char*)d_ws;
  size_t off = 0;
  ushort* xb     = (ushort*)(ws + off); off += (size_t)TT * BB * II * 2;     // 33.5 MB
  ushort* h0ring = (ushort*)(ws + off); off += (size_t)RING * BB * HH * 2;   // 1 MB
  ushort* h1ring = (ushort*)(ws + off); off += (size_t)RING * BB * HH * 2;   // 1 MB
  int* h0seq = (int*)(ws + off); off += SEQN * sizeof(int);                  // 64 KB
  int* h1seq = (int*)(ws + off); off += SEQN * sizeof(int);                  // 64 KB

  k_convert_x<<<2048, 256, 0, stream>>>(x, xb, TT * BB * II / 4);
  k_init<<<1, 256, 0, stream>>>(h0, h0ring, h1ring, h0seq, h1seq);
  k_lstm<<<NWG, 64, 0, stream>>>(xb, w_ih0, w_hh0, b_ih0, b_hh0,
                                 w_ih1, w_hh1, b_ih1, b_hh1, c0,
                                 h0ring, h1ring, h0seq, h1seq);
  // h1[2047] lives in ring slot 2047&31 = 31
  k_fc<<<BB, 256, 0, stream>>>(h1ring + (RING - 1) * BB * HH, fcw, fcb, out);
}

// Round 13
// 18022.720 us; speedup vs baseline: 1.0000x; 1.0000x over previous
//
#include <hip/hip_runtime.h>
#include <stdint.h>

// Problem dims
#define TT 2048
#define BB 32
#define II 256
#define HH 512
#define OO 1024
#define NWGL 16    // WGs per layer; 4 waves each; wave g = G*4+w owns units [8g,8g+8)
#define NWG 32
#define RING 32
#define SLOTB (BB * HH * 2)  // 32 KB

typedef __attribute__((ext_vector_type(8))) short short8;
typedef __attribute__((ext_vector_type(4))) float floatx4;

__device__ __forceinline__ unsigned short f2bf(float f) {
  union { float f; unsigned u; } v; v.f = f;
  unsigned r = v.u + 0x7FFFu + ((v.u >> 16) & 1u);  // RNE
  return (unsigned short)(r >> 16);
}
__device__ __forceinline__ float bf2f(unsigned short b) {
  union { float f; unsigned u; } v; v.u = ((unsigned)b) << 16; return v.f;
}
__device__ __forceinline__ float sigmf(float x) { return 1.0f / (1.0f + __expf(-x)); }
__device__ __forceinline__ float tanhfast(float x) {
  float xc = fminf(fmaxf(x, -15.f), 15.f);
  float e = __expf(2.f * xc);
  return (e - 1.f) / (e + 1.f);
}

// Coherent (MALL) 16B load: d <- [va + IMM], bypassing L1/L2.
#define LD1(d, va, IMM)                                                     \
  asm volatile("global_load_dwordx4 %0, %1, off offset:" IMM " sc0 sc1"     \
               : "=v"(d) : "v"(va) : "memory")

// 8KB staging issue: 8 x 1KB-wide loads (va must include +lane*16).
#define ISSUE8KB(dst, va) do {                                              \
    unsigned long long _v1 = (va), _v2 = (va) + 4096;                       \
    LD1(dst[0], _v1, "0");    LD1(dst[1], _v1, "1024");                     \
    LD1(dst[2], _v1, "2048"); LD1(dst[3], _v1, "3072");                     \
    LD1(dst[4], _v2, "0");    LD1(dst[5], _v2, "1024");                     \
    LD1(dst[6], _v2, "2048"); LD1(dst[7], _v2, "3072"); } while (0)

#define WAITV(N) do {                                                       \
    asm volatile("s_waitcnt vmcnt(" #N ")" ::: "memory");                   \
    __builtin_amdgcn_sched_barrier(0); } while (0)

// Swizzled LDS tile write: buf[j] -> row (w8+j), byte col (lane*16)^(j*16).
#define DSW8(buf, tile, w8) do {                                            \
    _Pragma("unroll")                                                       \
    for (int j = 0; j < 8; j++)                                             \
      *reinterpret_cast<short8*>(&(tile)[((w8) + j) * 512 + (lane ^ j) * 8]) = (buf)[j]; \
    } while (0)

// Swizzled LDS A-fragment read: tile row b, K-fragment kk (64B), sub krow.
#define LDSA(tile, b, kk)                                                   \
  (*reinterpret_cast<const short8*>(&(tile)[(b) * 512 + (((kk) * 4 + krow) ^ c7) * 8]))

#define PROGREAD(dst, addr64)                                               \
  asm volatile("global_load_dword %0, %1, off sc0 sc1"                      \
               : "=v"(dst) : "v"(addr64) : "memory")

#define SEQSTORE(arr, slot, val) do {                                       \
    if (lane == 0) {                                                        \
      unsigned long long _a = (unsigned long long)(arr) +                   \
          (unsigned long long)((slot) * 64 + g) * 4;                        \
      int _v = (val);                                                       \
      asm volatile("global_store_dword %0, %1, off sc0 sc1"                 \
                   :: "v"(_a), "v"(_v) : "memory");                         \
    } } while (0)

#define VALIDATE(arr, slot, tag) do {                                       \
    const unsigned long long _sa = (unsigned long long)(arr) +              \
        (unsigned long long)((slot) * 64 + lane) * 4;                       \
    int _sv; PROGREAD(_sv, _sa); WAITV(0);                                  \
    while (!__all(_sv == (tag))) {                                          \
      __builtin_amdgcn_s_sleep(1); PROGREAD(_sv, _sa); WAITV(0);            \
    } } while (0)

#define TAIL(hwaddr) do {                                                   \
  _Pragma("unroll")                                                         \
  for (int tau = 0; tau < 2; tau++) {                                       \
    _Pragma("unroll")                                                       \
    for (int tt = 0; tt < 2; tt++) {                                        \
      _Pragma("unroll")                                                     \
      for (int r = 0; r < 4; r++) {                                         \
        float val = acc[tau][tt][r];                                        \
        float nl = (gate == 2) ? tanhfast(val) : sigmf(val);                \
        int base2 = (lane & 48) | u;                                        \
        float iv = __shfl(nl, base2);                                       \
        float fv = __shfl(nl, base2 | 4);                                   \
        float gv = __shfl(nl, base2 | 8);                                   \
        float ov = __shfl(nl, base2 | 12);                                  \
        if (gate == 0) {                                                    \
          float cn = fv * cst[tau][tt][r] + iv * gv;                        \
          cst[tau][tt][r] = cn;                                             \
          float hn = ov * tanhfast(cn);                                     \
          int b = tt * 16 + krow * 4 + r;                                   \
          sh[w][b][tau * 4 + u] = f2bf(hn);                                 \
        }                                                                   \
      }                                                                     \
    }                                                                       \
  }                                                                         \
  asm volatile("s_waitcnt lgkmcnt(0)" ::: "memory");                        \
  __builtin_amdgcn_sched_barrier(0);                                        \
  if (lane < 32) {                                                          \
    short8 v = *reinterpret_cast<const short8*>(&sh[w][lane][0]);           \
    unsigned long long sa = (hwaddr) + stoff;                               \
    asm volatile("global_store_dwordx4 %0, %1, off sc0 sc1"                 \
                 :: "v"(sa), "v"(v) : "memory");                            \
  } } while (0)

// ---------------- x fp32 -> bf16 convert ----------------
__global__ void k_convert_x(const float* __restrict__ x, ushort* __restrict__ xb, int n4) {
  int i = blockIdx.x * blockDim.x + threadIdx.x;
  int stride = gridDim.x * blockDim.x;
  const float4* xf = reinterpret_cast<const float4*>(x);
  ushort4* ob = reinterpret_cast<ushort4*>(xb);
  for (; i < n4; i += stride) {
    float4 f = xf[i];
    ushort4 o;
    o.x = f2bf(f.x); o.y = f2bf(f.y); o.z = f2bf(f.z); o.w = f2bf(f.w);
    ob[i] = o;
  }
}

// ---------------- init ----------------
__global__ void k_init(const float* __restrict__ h0in,
                       ushort* __restrict__ h0ring, ushort* __restrict__ h1ring,
                       int* __restrict__ h0seq, int* __restrict__ h1seq,
                       int* __restrict__ pr1) {
  int i = threadIdx.x;
  ushort* s0 = h0ring + (RING - 1) * BB * HH;
  ushort* s1 = h1ring + (RING - 1) * BB * HH;
  for (int k = i; k < BB * HH; k += blockDim.x) {
    s0[k] = f2bf(h0in[k]);
    s1[k] = f2bf(h0in[BB * HH + k]);
  }
  for (int k = i; k < RING * 64; k += blockDim.x) {
    int v = (k >= (RING - 1) * 64) ? -1 : (int)0x80000000;
    h0seq[k] = v;
    h1seq[k] = v;
  }
  for (int k = i; k < 64; k += blockDim.x) pr1[k] = -1;
}

// ---------------- persistent recurrence kernel (LDS-shared reads) ----------
// 32 WGs x 4 waves. r6's protocol per wave (tags g, rings, c-state, stores)
// is unchanged; the h data path stages each tile ONCE per WG into swizzled
// LDS (each wave loads 8KB), then all A-fragments come from LDS. Coherent
// read demand drops 4x (the measured 6.2us/phase load burst). Wave0 polls;
// teammates gated by the staging barrier.
__global__ __launch_bounds__(256, 1) void k_lstm(
    const ushort* __restrict__ xb,
    const float* __restrict__ w_ih0, const float* __restrict__ w_hh0,
    const float* __restrict__ b_ih0, const float* __restrict__ b_hh0,
    const float* __restrict__ w_ih1, const float* __restrict__ w_hh1,
    const float* __restrict__ b_ih1, const float* __restrict__ b_hh1,
    const float* __restrict__ c0in,
    ushort* __restrict__ h0ring, ushort* __restrict__ h1ring,
    int* __restrict__ h0seq, int* __restrict__ h1seq,
    int* __restrict__ pr1)
{
  __shared__ ushort t0[32 * 512];      // 32KB tile (L0: h0[t-1]; L1: h0[t])
  __shared__ ushort t1[32 * 512];      // 32KB tile (L1: h1[t-1]; L0 unused)
  __shared__ ushort sh[4][BB][8];      // per-wave store-pack tiles
  const int wg = blockIdx.x;
  const int tid = threadIdx.x;
  const int w = tid >> 6;
  const int lane = tid & 63;
  const bool isL0 = wg < NWGL;
  const int G = isL0 ? wg : wg - NWGL;
  const int g = G * 4 + w;             // wave id within layer, 0..63 (as r6)
  const int col = lane & 15;
  const int krow = lane >> 4;
  const int u = col & 3;
  const int gate = col >> 2;
  const int c7 = col & 7;

  // --- pack weight B-fragments into registers (bf16) --- (r6 verbatim)
  short8 wf[2][32];
#define LOADW(dst, base, rowlen, kbase, tau) do {                             \
    const int _grow = gate * HH + g * 8 + (tau) * 4 + u;                      \
    const float* _p = (base) + (size_t)_grow * (rowlen) + (kbase) + krow * 8; \
    short8 _r;                                                                \
    _Pragma("unroll")                                                         \
    for (int _j = 0; _j < 8; _j++) _r[_j] = (short)f2bf(_p[_j]);              \
    (dst) = _r; } while (0)

  if (isL0) {
#pragma unroll
    for (int tau = 0; tau < 2; tau++) {
#pragma unroll
      for (int kk = 0; kk < 8; kk++)  LOADW(wf[tau][kk],      w_ih0, II, kk * 32, tau);
#pragma unroll
      for (int kk = 0; kk < 16; kk++) LOADW(wf[tau][8 + kk],  w_hh0, HH, kk * 32, tau);
    }
  } else {
#pragma unroll
    for (int tau = 0; tau < 2; tau++) {
#pragma unroll
      for (int kk = 0; kk < 16; kk++) LOADW(wf[tau][kk],      w_ih1, HH, kk * 32, tau);
#pragma unroll
      for (int kk = 0; kk < 16; kk++) LOADW(wf[tau][16 + kk], w_hh1, HH, kk * 32, tau);
    }
  }
  float bias[2];
#pragma unroll
  for (int tau = 0; tau < 2; tau++) {
    const int grow = gate * HH + g * 8 + tau * 4 + u;
    bias[tau] = isL0 ? (b_ih0[grow] + b_hh0[grow]) : (b_ih1[grow] + b_hh1[grow]);
  }

  float cst[2][2][4];
  {
    const float* cbase = c0in + (isL0 ? 0 : 1) * BB * HH;
#pragma unroll
    for (int tau = 0; tau < 2; tau++)
#pragma unroll
      for (int tt = 0; tt < 2; tt++)
#pragma unroll
        for (int r = 0; r < 4; r++) {
          int b = tt * 16 + krow * 4 + r;
          cst[tau][tt][r] = cbase[b * HH + g * 8 + tau * 4 + u];
        }
  }

  const unsigned long long h0rb = (unsigned long long)h0ring;
  const unsigned long long h1rb = (unsigned long long)h1ring;
  const unsigned long long stoff = (unsigned long long)(lane * 1024 + g * 16);
  const unsigned long long stagevo = (unsigned long long)(w * 8192 + lane * 16);

  short8 wa[8], wb[8];
  floatx4 acc[2][2];
  const floatx4 bi0 = (floatx4){ bias[0], bias[0], bias[0], bias[0] };
  const floatx4 bi1 = (floatx4){ bias[1], bias[1], bias[1], bias[1] };

  if (isL0) {
    // =============== layer 0 ===============
    for (int t = 0; t < TT; ++t) {
      if (w == 0) {
        VALIDATE(h0seq, (t + 31) & 31, t - 1);
        if (((t & 7) == 0) && t >= 32) {
          const unsigned long long pa = (unsigned long long)pr1 + lane * 4ull;
          int pv; PROGREAD(pv, pa); WAITV(0);
          while (!__all(pv >= t - 24)) {
            __builtin_amdgcn_s_sleep(4); PROGREAD(pv, pa); WAITV(0);
          }
        }
      }
      __syncthreads();  // gates staging on wave0's validation; protects t0 reuse
      // ---- stage h0[t-1] quarter into swizzled LDS ----
      ISSUE8KB(wa, h0rb + (unsigned long long)((t + 31) & 31) * SLOTB + stagevo);
      WAITV(0);
      DSW8(wa, t0, w * 8);
      __syncthreads();
      // ---- compute: x (cached, per-wave) + h0 (LDS) ----
      acc[0][0] = bi0; acc[0][1] = bi0; acc[1][0] = bi1; acc[1][1] = bi1;
      const char* xr = (const char*)xb + (size_t)t * (BB * II * 2);
#pragma unroll
      for (int tt = 0; tt < 2; tt++) {
        const int b = tt * 16 + col;
#pragma unroll
        for (int kk = 0; kk < 8; kk++) {
          short8 a = *reinterpret_cast<const short8*>(xr + b * 512 + kk * 64 + krow * 16);
          acc[0][tt] = __builtin_amdgcn_mfma_f32_16x16x32_bf16(a, wf[0][kk], acc[0][tt], 0, 0, 0);
          acc[1][tt] = __builtin_amdgcn_mfma_f32_16x16x32_bf16(a, wf[1][kk], acc[1][tt], 0, 0, 0);
        }
#pragma unroll
        for (int kk = 0; kk < 16; kk++) {
          short8 a = LDSA(t0, b, kk);
          acc[0][tt] = __builtin_amdgcn_mfma_f32_16x16x32_bf16(a, wf[0][8 + kk], acc[0][tt], 0, 0, 0);
          acc[1][tt] = __builtin_amdgcn_mfma_f32_16x16x32_bf16(a, wf[1][8 + kk], acc[1][tt], 0, 0, 0);
        }
      }
      TAIL(h0rb + (unsigned long long)(t & 31) * SLOTB);
      WAITV(0);                        // drain h stores
      SEQSTORE(h0seq, (t & 31), t);    // publish
    }
  } else {
    // =============== layer 1 ===============
    for (int t = 0; t < TT; ++t) {
      if (w == 0) {
        const unsigned long long sa0 = (unsigned long long)h0seq +
            (unsigned long long)((t & 31) * 64 + lane) * 4;
        const unsigned long long sa1 = (unsigned long long)h1seq +
            (unsigned long long)(((t + 31) & 31) * 64 + lane) * 4;
        int s0, s1; PROGREAD(s0, sa0); PROGREAD(s1, sa1); WAITV(0);
        while (!(__all(s0 == t) & __all(s1 == t - 1))) {
          __builtin_amdgcn_s_sleep(1);
          PROGREAD(s0, sa0); PROGREAD(s1, sa1); WAITV(0);
        }
      }
      __syncthreads();
      // ---- stage h0[t] + h1[t-1] quarters into swizzled LDS ----
      ISSUE8KB(wa, h0rb + (unsigned long long)(t & 31) * SLOTB + stagevo);
      ISSUE8KB(wb, h1rb + (unsigned long long)((t + 31) & 31) * SLOTB + stagevo);
      WAITV(8);
      DSW8(wa, t0, w * 8);
      WAITV(0);
      DSW8(wb, t1, w * 8);
      // publish consume progress (this wave's reads of both slots complete)
      if (lane == 0) {
        unsigned long long pa = (unsigned long long)pr1 + (unsigned long long)g * 4;
        int pv = t;
        asm volatile("global_store_dword %0, %1, off sc0 sc1"
                     :: "v"(pa), "v"(pv) : "memory");
      }
      __syncthreads();
      // ---- compute: h0 (LDS t0) + h1 (LDS t1) ----
      acc[0][0] = bi0; acc[0][1] = bi0; acc[1][0] = bi1; acc[1][1] = bi1;
#pragma unroll
      for (int tt = 0; tt < 2; tt++) {
        const int b = tt * 16 + col;
#pragma unroll
        for (int kk = 0; kk < 16; kk++) {
          short8 a = LDSA(t0, b, kk);
          acc[0][tt] = __builtin_amdgcn_mfma_f32_16x16x32_bf16(a, wf[0][kk], acc[0][tt], 0, 0, 0);
          acc[1][tt] = __builtin_amdgcn_mfma_f32_16x16x32_bf16(a, wf[1][kk], acc[1][tt], 0, 0, 0);
        }
#pragma unroll
        for (int kk = 0; kk < 16; kk++) {
          short8 a = LDSA(t1, b, kk);
          acc[0][tt] = __builtin_amdgcn_mfma_f32_16x16x32_bf16(a, wf[0][16 + kk], acc[0][tt], 0, 0, 0);
          acc[1][tt] = __builtin_amdgcn_mfma_f32_16x16x32_bf16(a, wf[1][16 + kk], acc[1][tt], 0, 0, 0);
        }
      }
      TAIL(h1rb + (unsigned long long)(t & 31) * SLOTB);
      WAITV(0);
      SEQSTORE(h1seq, (t & 31), t);
    }
  }
}

// ---------------- FC + log_softmax ----------------
__global__ __launch_bounds__(256) void k_fc(const ushort* __restrict__ h1,
                                            const float* __restrict__ fcw,
                                            const float* __restrict__ fcb,
                                            float* __restrict__ out) {
  __shared__ float hsh[HH];
  __shared__ float red[256];
  const int b = blockIdx.x, tid = threadIdx.x;
  for (int k = tid; k < HH; k += 256) hsh[k] = bf2f(h1[b * HH + k]);
  __syncthreads();
  float lg[4];
#pragma unroll
  for (int q = 0; q < 4; q++) {
    int o = q * 256 + tid;
    float acc = fcb[o];
    const float* wr = fcw + (size_t)o * HH;
#pragma unroll 4
    for (int k = 0; k < HH; k += 4) {
      float4 w4 = *reinterpret_cast<const float4*>(wr + k);
      acc += hsh[k] * w4.x + hsh[k + 1] * w4.y + hsh[k + 2] * w4.z + hsh[k + 3] * w4.w;
    }
    lg[q] = acc;
  }
  float m = fmaxf(fmaxf(lg[0], lg[1]), fmaxf(lg[2], lg[3]));
  red[tid] = m; __syncthreads();
  for (int s = 128; s > 0; s >>= 1) { if (tid < s) red[tid] = fmaxf(red[tid], red[tid + s]); __syncthreads(); }
  m = red[0]; __syncthreads();
  float se = 0.f;
#pragma unroll
  for (int q = 0; q < 4; q++) se += __expf(lg[q] - m);
  red[tid] = se; __syncthreads();
  for (int s = 128; s > 0; s >>= 1) { if (tid < s) red[tid] += red[tid + s]; __syncthreads(); }
  float lse = m + logf(red[0]);
#pragma unroll
  for (int q = 0; q < 4; q++) out[b * OO + q * 256 + tid] = lg[q] - lse;
}

extern "C" void kernel_launch(void* const* d_in, const int* in_sizes, int n_in,
                              void* d_out, int out_size, void* d_ws, size_t ws_size,
                              hipStream_t stream) {
  const float* x     = (const float*)d_in[0];
  const float* h0    = (const float*)d_in[1];
  const float* c0    = (const float*)d_in[2];
  const float* w_ih0 = (const float*)d_in[3];
  const float* w_hh0 = (const float*)d_in[4];
  const float* b_ih0 = (const float*)d_in[5];
  const float* b_hh0 = (const float*)d_in[6];
  const float* w_ih1 = (const float*)d_in[7];
  const float* w_hh1 = (const float*)d_in[8];
  const float* b_ih1 = (const float*)d_in[9];
  const float* b_hh1 = (const float*)d_in[10];
  const float* fcw   = (const float*)d_in[11];
  const float* fcb   = (const float*)d_in[12];
  float* out = (float*)d_out;

  char* ws = (char*)d_ws;
  size_t off = 0;
  ushort* xb     = (ushort*)(ws + off); off += (size_t)TT * BB * II * 2;
  ushort* h0ring = (ushort*)(ws + off); off += (size_t)RING * BB * HH * 2;
  ushort* h1ring = (ushort*)(ws + off); off += (size_t)RING * BB * HH * 2;
  int* h0seq = (int*)(ws + off); off += RING * 64 * sizeof(int);
  int* h1seq = (int*)(ws + off); off += RING * 64 * sizeof(int);
  int* pr1   = (int*)(ws + off); off += 64 * sizeof(int);

  k_convert_x<<<2048, 256, 0, stream>>>(x, xb, TT * BB * II / 4);
  k_init<<<1, 256, 0, stream>>>(h0, h0ring, h1ring, h0seq, h1seq, pr1);
  k_lstm<<<NWG, 256, 0, stream>>>(xb, w_ih0, w_hh0, b_ih0, b_hh0,
                                  w_ih1, w_hh1, b_ih1, b_hh1, c0,
                                  h0ring, h1ring, h0seq, h1seq, pr1);
  // h1[2047] lives in ring slot 2047&31 = 31
  k_fc<<<BB, 256, 0, stream>>>(h1ring + (RING - 1) * BB * HH, fcw, fcb, out);
}